// Round 1
// baseline (487.716 us; speedup 1.0000x reference)
//
#include <hip/hip_runtime.h>

#define NNODES 25000
#define NEDGES 200000
#define ETOT   (NNODES + NEDGES)
#define HC     256   // H*C
#define CCH    64

// ---------------- xw = x @ W  (x: [N,D], W: [D,256]) ----------------
template<int D>
__global__ void xw_kernel(const float* __restrict__ x, const float* __restrict__ W,
                          float* __restrict__ xw, int n_nodes) {
    const int NB = 8;
    __shared__ float xs[NB][D];
    int base = blockIdx.x * NB;
    int tid = threadIdx.x;
    for (int i = tid; i < NB * D; i += 256) {
        int node = base + i / D;
        xs[i / D][i % D] = (node < n_nodes) ? x[node * D + (i % D)] : 0.f;
    }
    __syncthreads();
    float acc[NB];
#pragma unroll
    for (int i = 0; i < NB; i++) acc[i] = 0.f;
    int j = tid;  // output column 0..255
    for (int k = 0; k < D; k++) {
        float w = W[k * 256 + j];
#pragma unroll
        for (int i = 0; i < NB; i++) acc[i] += xs[i][k] * w;
    }
#pragma unroll
    for (int i = 0; i < NB; i++) {
        int node = base + i;
        if (node < n_nodes) xw[node * 256 + j] = acc[i];
    }
}

// ---------------- per-edge attention + message + scatter ----------------
template<int D>
__global__ void edge_kernel(const float* __restrict__ x, const float* __restrict__ xw,
                            const int* __restrict__ esrc, const int* __restrict__ edst,
                            const float* __restrict__ U, const float* __restrict__ cvec,
                            float* __restrict__ agg) {
    int wid = threadIdx.x >> 6;
    int lane = threadIdx.x & 63;
    int e = blockIdx.x * 4 + wid;
    if (e >= ETOT) return;
    int s, d;
    if (e < NEDGES) { s = esrc[e]; d = edst[e]; }
    else            { s = e - NEDGES; d = s; }

    float l0 = 0.f, l1 = 0.f, l2 = 0.f, l3 = 0.f;
    if (lane < D) {
        float xd = x[d * D + lane] - x[s * D + lane];
        l0 = xd * U[lane * 4 + 0];
        l1 = xd * U[lane * 4 + 1];
        l2 = xd * U[lane * 4 + 2];
        l3 = xd * U[lane * 4 + 3];
    }
#pragma unroll
    for (int m = 1; m < 64; m <<= 1) {
        l0 += __shfl_xor(l0, m);
        l1 += __shfl_xor(l1, m);
        l2 += __shfl_xor(l2, m);
        l3 += __shfl_xor(l3, m);
    }
    l0 += cvec[0]; l1 += cvec[1]; l2 += cvec[2]; l3 += cvec[3];
    float mx = fmaxf(fmaxf(l0, l1), fmaxf(l2, l3));
    float e0 = __expf(l0 - mx), e1 = __expf(l1 - mx), e2 = __expf(l2 - mx), e3 = __expf(l3 - mx);
    float inv = 1.f / (e0 + e1 + e2 + e3);
    e0 *= inv; e1 *= inv; e2 *= inv; e3 *= inv;

    const float* xwr = xw + (size_t)s * 256;
    float v = e0 * xwr[lane] + e1 * xwr[64 + lane] + e2 * xwr[128 + lane] + e3 * xwr[192 + lane];
    atomicAdd(&agg[d * 64 + lane], v);
}

// ---------------- degree count ----------------
__global__ void init_cnt(float* __restrict__ cnt, int n) {
    int i = blockIdx.x * blockDim.x + threadIdx.x;
    if (i < n) cnt[i] = 1.0f;  // self loop
}
__global__ void cnt_kernel(const int* __restrict__ edst, float* __restrict__ cnt) {
    int i = blockIdx.x * blockDim.x + threadIdx.x;
    if (i < NEDGES) atomicAdd(&cnt[edst[i]], 1.0f);
}

// ---------------- finalize: y = relu(agg/cnt + b), accumulate BN sums ----------------
__global__ void finalize_bn_sums(const float* __restrict__ agg, const float* __restrict__ cnt,
                                 const float* __restrict__ b, float* __restrict__ y,
                                 float* __restrict__ gsum, float* __restrict__ gsq) {
    int tid = threadIdx.x;
    int total = NNODES * 64;
    float s = 0.f, sq = 0.f;
    for (int i = blockIdx.x * 256 + tid; i < total; i += gridDim.x * 256) {
        int ch = i & 63;
        float v = agg[i] / cnt[i >> 6] + b[ch];
        v = fmaxf(v, 0.f);
        y[i] = v;
        s += v; sq += v * v;
    }
    __shared__ float ssum[256], ssq[256];
    ssum[tid] = s; ssq[tid] = sq;
    __syncthreads();
    if (tid < 64) {
        float ts = ssum[tid] + ssum[tid + 64] + ssum[tid + 128] + ssum[tid + 192];
        float tq = ssq[tid] + ssq[tid + 64] + ssq[tid + 128] + ssq[tid + 192];
        atomicAdd(&gsum[tid], ts);
        atomicAdd(&gsq[tid], tq);
    }
}

// ---------------- BN apply (training-mode, biased var) ----------------
__global__ void bn_apply(float* __restrict__ y, const float* __restrict__ gsum,
                         const float* __restrict__ gsq, const float* __restrict__ g,
                         const float* __restrict__ be) {
    int idx = blockIdx.x * blockDim.x + threadIdx.x;
    int total = NNODES * 64;
    if (idx >= total) return;
    int ch = idx & 63;
    float m = gsum[ch] * (1.0f / NNODES);
    float v = gsq[ch] * (1.0f / NNODES) - m * m;
    y[idx] = (y[idx] - m) * rsqrtf(v + 1e-5f) * g[ch] + be[ch];
}

// ---------------- final layer output: agg/cnt + b ----------------
__global__ void finalize_out(const float* __restrict__ agg, const float* __restrict__ cnt,
                             const float* __restrict__ b, float* __restrict__ out) {
    int idx = blockIdx.x * blockDim.x + threadIdx.x;
    int total = NNODES * 64;
    if (idx >= total) return;
    out[idx] = agg[idx] / cnt[idx >> 6] + b[idx & 63];
}

extern "C" void kernel_launch(void* const* d_in, const int* in_sizes, int n_in,
                              void* d_out, int out_size, void* d_ws, size_t ws_size,
                              hipStream_t stream) {
    const float* x    = (const float*)d_in[0];
    const int*   ei   = (const int*)d_in[1];
    const int*   esrc = ei;
    const int*   edst = ei + NEDGES;
    const float* w0 = (const float*)d_in[2];
    const float* u0 = (const float*)d_in[3];
    const float* c0 = (const float*)d_in[4];
    const float* b0 = (const float*)d_in[5];
    const float* w1 = (const float*)d_in[6];
    const float* u1 = (const float*)d_in[7];
    const float* c1 = (const float*)d_in[8];
    const float* b1 = (const float*)d_in[9];
    const float* w2 = (const float*)d_in[10];
    const float* u2 = (const float*)d_in[11];
    const float* c2 = (const float*)d_in[12];
    const float* b2 = (const float*)d_in[13];
    const float* g0 = (const float*)d_in[14];
    const float* be0= (const float*)d_in[15];
    const float* g1 = (const float*)d_in[16];
    const float* be1= (const float*)d_in[17];
    float* out = (float*)d_out;

    float* ws   = (float*)d_ws;
    float* xw   = ws;                       // N*256
    float* agg  = xw  + (size_t)NNODES * 256; // N*64
    float* cnt  = agg + (size_t)NNODES * 64;  // N
    float* y    = cnt + NNODES;               // N*64
    float* gsum = y   + (size_t)NNODES * 64;  // 64
    float* gsq  = gsum + 64;                  // 64

    const int egrid = (ETOT + 3) / 4;

    // degree count (shared across layers)
    init_cnt<<<(NNODES + 255) / 256, 256, 0, stream>>>(cnt, NNODES);
    cnt_kernel<<<(NEDGES + 255) / 256, 256, 0, stream>>>(edst, cnt);

    // ---- layer 0 (D=32) ----
    hipMemsetAsync(agg, 0, (size_t)NNODES * 64 * sizeof(float), stream);
    hipMemsetAsync(gsum, 0, 2 * 64 * sizeof(float), stream);
    xw_kernel<32><<<(NNODES + 7) / 8, 256, 0, stream>>>(x, w0, xw, NNODES);
    edge_kernel<32><<<egrid, 256, 0, stream>>>(x, xw, esrc, edst, u0, c0, agg);
    finalize_bn_sums<<<640, 256, 0, stream>>>(agg, cnt, b0, y, gsum, gsq);
    bn_apply<<<(NNODES * 64 + 255) / 256, 256, 0, stream>>>(y, gsum, gsq, g0, be0);

    // ---- layer 1 (D=64) ----
    hipMemsetAsync(agg, 0, (size_t)NNODES * 64 * sizeof(float), stream);
    hipMemsetAsync(gsum, 0, 2 * 64 * sizeof(float), stream);
    xw_kernel<64><<<(NNODES + 7) / 8, 256, 0, stream>>>(y, w1, xw, NNODES);
    edge_kernel<64><<<egrid, 256, 0, stream>>>(y, xw, esrc, edst, u1, c1, agg);
    finalize_bn_sums<<<640, 256, 0, stream>>>(agg, cnt, b1, y, gsum, gsq);
    bn_apply<<<(NNODES * 64 + 255) / 256, 256, 0, stream>>>(y, gsum, gsq, g1, be1);

    // ---- layer 2 (D=64, no relu/bn) ----
    hipMemsetAsync(agg, 0, (size_t)NNODES * 64 * sizeof(float), stream);
    xw_kernel<64><<<(NNODES + 7) / 8, 256, 0, stream>>>(y, w2, xw, NNODES);
    edge_kernel<64><<<egrid, 256, 0, stream>>>(y, xw, esrc, edst, u2, c2, agg);
    finalize_out<<<(NNODES * 64 + 255) / 256, 256, 0, stream>>>(agg, cnt, b2, out);
}

// Round 2
// 248.918 us; speedup vs baseline: 1.9593x; 1.9593x over previous
//
#include <hip/hip_runtime.h>

#define NN 25000
#define NE 200000
#define ET (NN + NE)

__device__ __forceinline__ unsigned short f2bf(float f) {
    unsigned u = __float_as_uint(f);
    unsigned r = (u + 0x7fffu + ((u >> 16) & 1u)) >> 16;
    return (unsigned short)r;
}
__device__ __forceinline__ float bf2f(unsigned short h) {
    return __uint_as_float(((unsigned)h) << 16);
}

// ---------- CSR build ----------
__global__ void hist_kernel(const int* __restrict__ edst, int* __restrict__ deg) {
    int e = blockIdx.x * 256 + threadIdx.x;
    if (e >= ET) return;
    int d = (e < NE) ? edst[e] : (e - NE);
    atomicAdd(&deg[d], 1);
}

__global__ void scan_kernel(const int* __restrict__ deg, int* __restrict__ rowptr,
                            int* __restrict__ cursor) {
    __shared__ int part[1024];
    int t = threadIdx.x;
    const int PER = (NN + 1023) / 1024;  // 25
    int beg = t * PER;
    int end = min(beg + PER, NN);
    int s = 0;
    for (int i = beg; i < end; i++) s += deg[i];
    part[t] = s;
    __syncthreads();
    for (int off = 1; off < 1024; off <<= 1) {
        int v = (t >= off) ? part[t - off] : 0;
        __syncthreads();
        part[t] += v;
        __syncthreads();
    }
    int run = (t == 0) ? 0 : part[t - 1];
    for (int i = beg; i < end; i++) {
        rowptr[i] = run;
        cursor[i] = run;
        run += deg[i];
    }
    if (t == 1023) rowptr[NN] = run;  // = ET (last chunks empty, run = total)
}

__global__ void scatter_kernel(const int* __restrict__ esrc, const int* __restrict__ edst,
                               int* __restrict__ cursor, int* __restrict__ srcs) {
    int e = blockIdx.x * 256 + threadIdx.x;
    if (e >= ET) return;
    int s, d;
    if (e < NE) { s = esrc[e]; d = edst[e]; }
    else        { s = e - NE; d = s; }
    int p = atomicAdd(&cursor[d], 1);
    srcs[p] = s;
}

// ---------- xw = bn(x) @ W  (bf16 out, [n][h][c]) + xu = bn(x) @ U ----------
template<int D, bool BN>
__global__ void xw_kernel(const float* __restrict__ x, const float* __restrict__ W,
                          const float* __restrict__ U, const float* __restrict__ ss,
                          unsigned short* __restrict__ xwb, float* __restrict__ xu) {
    const int NB = 8;  // 25000 % 8 == 0
    __shared__ float xs[NB][D];
    int base = blockIdx.x * NB;
    int tid = threadIdx.x;
    for (int i = tid; i < NB * D; i += 256) {
        int n = i / D, k = i % D;
        float v = x[(size_t)(base + n) * D + k];
        if (BN) v = v * ss[k] + ss[64 + k];
        xs[n][k] = v;
    }
    __syncthreads();
    float acc[NB];
#pragma unroll
    for (int i = 0; i < NB; i++) acc[i] = 0.f;
    int j = tid;  // h*64+c
    for (int k = 0; k < D; k++) {
        float w = W[k * 256 + j];
#pragma unroll
        for (int i = 0; i < NB; i++) acc[i] += xs[i][k] * w;
    }
#pragma unroll
    for (int i = 0; i < NB; i++) xwb[(size_t)(base + i) * 256 + j] = f2bf(acc[i]);
    // xu: threads 0..31 -> (node, head)
    if (tid < NB * 4) {
        int n = tid >> 2, h = tid & 3;
        float s = 0.f;
        for (int k = 0; k < D; k++) s += xs[n][k] * U[k * 4 + h];
        xu[(size_t)(base + n) * 4 + h] = s;
    }
}

// ---------- edge aggregation: wave per dst ----------
template<bool RELU_BN>
__global__ void edge_kernel(const int* __restrict__ rowptr, const int* __restrict__ srcs,
                            const unsigned short* __restrict__ xwb, const float* __restrict__ xu,
                            const float* __restrict__ cvec, const float* __restrict__ bias,
                            float* __restrict__ y, float* __restrict__ bnpart) {
    int wid = threadIdx.x >> 6, lane = threadIdx.x & 63;
    int d = blockIdx.x * 4 + wid;  // grid 6250 * 4 waves == 25000 exactly
    __shared__ float sbuf[4][64], sqbuf[4][64];

    float c0 = cvec[0], c1 = cvec[1], c2 = cvec[2], c3 = cvec[3];
    int beg = rowptr[d], end = rowptr[d + 1];
    float xd0 = xu[d * 4 + 0], xd1 = xu[d * 4 + 1], xd2 = xu[d * 4 + 2], xd3 = xu[d * 4 + 3];
    float acc = 0.f;
    int s = srcs[beg];
    for (int i = beg; i < end; i++) {
        int snext = (i + 1 < end) ? srcs[i + 1] : s;
        float4 us = *(const float4*)&xu[s * 4];
        float l0 = xd0 - us.x + c0;
        float l1 = xd1 - us.y + c1;
        float l2 = xd2 - us.z + c2;
        float l3 = xd3 - us.w + c3;
        float mx = fmaxf(fmaxf(l0, l1), fmaxf(l2, l3));
        float e0 = __expf(l0 - mx), e1 = __expf(l1 - mx), e2 = __expf(l2 - mx), e3 = __expf(l3 - mx);
        float inv = 1.f / (e0 + e1 + e2 + e3);
        const unsigned short* r = xwb + (size_t)s * 256 + lane;
        float w0 = bf2f(r[0]), w1 = bf2f(r[64]), w2 = bf2f(r[128]), w3 = bf2f(r[192]);
        acc += inv * (e0 * w0 + e1 * w1 + e2 * w2 + e3 * w3);
        s = snext;
    }
    float v = acc / (float)(end - beg) + bias[lane];
    if (RELU_BN) v = fmaxf(v, 0.f);
    y[(size_t)d * 64 + lane] = v;

    if (RELU_BN) {
        sbuf[wid][lane] = v;
        sqbuf[wid][lane] = v * v;
        __syncthreads();
        if (threadIdx.x < 64) {
            float ts = sbuf[0][threadIdx.x] + sbuf[1][threadIdx.x] + sbuf[2][threadIdx.x] + sbuf[3][threadIdx.x];
            float tq = sqbuf[0][threadIdx.x] + sqbuf[1][threadIdx.x] + sqbuf[2][threadIdx.x] + sqbuf[3][threadIdx.x];
            int p = blockIdx.x & 63;
            atomicAdd(&bnpart[p * 128 + threadIdx.x], ts);
            atomicAdd(&bnpart[p * 128 + 64 + threadIdx.x], tq);
        }
    }
}

// ---------- BN stats -> scale/shift ----------
__global__ void bnprep(const float* __restrict__ bnpart, const float* __restrict__ g,
                       const float* __restrict__ be, float* __restrict__ ss) {
    int ch = threadIdx.x;  // 64 threads
    float s = 0.f, q = 0.f;
    for (int p = 0; p < 64; p++) {
        s += bnpart[p * 128 + ch];
        q += bnpart[p * 128 + 64 + ch];
    }
    float m = s * (1.0f / NN);
    float v = q * (1.0f / NN) - m * m;
    float sc = g[ch] * rsqrtf(v + 1e-5f);
    ss[ch] = sc;
    ss[64 + ch] = be[ch] - m * sc;
}

extern "C" void kernel_launch(void* const* d_in, const int* in_sizes, int n_in,
                              void* d_out, int out_size, void* d_ws, size_t ws_size,
                              hipStream_t stream) {
    const float* x    = (const float*)d_in[0];
    const int*   ei   = (const int*)d_in[1];
    const int*   esrc = ei;
    const int*   edst = ei + NE;
    const float* w0 = (const float*)d_in[2];
    const float* u0 = (const float*)d_in[3];
    const float* c0 = (const float*)d_in[4];
    const float* b0 = (const float*)d_in[5];
    const float* w1 = (const float*)d_in[6];
    const float* u1 = (const float*)d_in[7];
    const float* c1 = (const float*)d_in[8];
    const float* b1 = (const float*)d_in[9];
    const float* w2 = (const float*)d_in[10];
    const float* u2 = (const float*)d_in[11];
    const float* c2 = (const float*)d_in[12];
    const float* b2 = (const float*)d_in[13];
    const float* g0 = (const float*)d_in[14];
    const float* be0= (const float*)d_in[15];
    const float* g1 = (const float*)d_in[16];
    const float* be1= (const float*)d_in[17];
    float* out = (float*)d_out;

    char* ws = (char*)d_ws;
    size_t off = 0;
    auto alloc = [&](size_t bytes) { char* p = ws + off; off += (bytes + 255) & ~(size_t)255; return p; };
    float*          xu     = (float*)alloc((size_t)NN * 4 * sizeof(float));
    float*          y      = (float*)alloc((size_t)NN * 64 * sizeof(float));
    unsigned short* xwb    = (unsigned short*)alloc((size_t)NN * 256 * sizeof(unsigned short));
    int*            deg    = (int*)alloc((size_t)NN * sizeof(int));
    int*            rowptr = (int*)alloc((size_t)(NN + 1) * sizeof(int));
    int*            cursor = (int*)alloc((size_t)NN * sizeof(int));
    int*            srcs   = (int*)alloc((size_t)ET * sizeof(int));
    float*          bnpart = (float*)alloc(64 * 128 * sizeof(float));
    float*          ss     = (float*)alloc(128 * sizeof(float));

    const int EG = (ET + 255) / 256;

    // ---- CSR build (dst-sorted; shared by all 3 layers) ----
    hipMemsetAsync(deg, 0, (size_t)NN * sizeof(int), stream);
    hist_kernel<<<EG, 256, 0, stream>>>(edst, deg);
    scan_kernel<<<1, 1024, 0, stream>>>(deg, rowptr, cursor);
    scatter_kernel<<<EG, 256, 0, stream>>>(esrc, edst, cursor, srcs);

    // ---- layer 0 (D=32, no BN on input) ----
    hipMemsetAsync(bnpart, 0, 64 * 128 * sizeof(float), stream);
    xw_kernel<32, false><<<NN / 8, 256, 0, stream>>>(x, w0, u0, nullptr, xwb, xu);
    edge_kernel<true><<<NN / 4, 256, 0, stream>>>(rowptr, srcs, xwb, xu, c0, b0, y, bnpart);
    bnprep<<<1, 64, 0, stream>>>(bnpart, g0, be0, ss);

    // ---- layer 1 (D=64, BN0 applied on load) ----
    hipMemsetAsync(bnpart, 0, 64 * 128 * sizeof(float), stream);
    xw_kernel<64, true><<<NN / 8, 256, 0, stream>>>(y, w1, u1, ss, xwb, xu);
    edge_kernel<true><<<NN / 4, 256, 0, stream>>>(rowptr, srcs, xwb, xu, c1, b1, y, bnpart);
    bnprep<<<1, 64, 0, stream>>>(bnpart, g1, be1, ss);

    // ---- layer 2 (D=64, BN1 applied on load, raw output) ----
    xw_kernel<64, true><<<NN / 8, 256, 0, stream>>>(y, w2, u2, ss, xwb, xu);
    edge_kernel<false><<<NN / 4, 256, 0, stream>>>(rowptr, srcs, xwb, xu, c2, b2, out, nullptr);
}

// Round 3
// 208.319 us; speedup vs baseline: 2.3412x; 1.1949x over previous
//
#include <hip/hip_runtime.h>

#define NN 25000
#define NE 200000
#define ET (NN + NE)
#define NBLK_SCAN ((NN + 255) / 256)   // 98

__device__ __forceinline__ unsigned short f2bf(float f) {
    unsigned u = __float_as_uint(f);
    unsigned r = (u + 0x7fffu + ((u >> 16) & 1u)) >> 16;
    return (unsigned short)r;
}
__device__ __forceinline__ float bf2f(unsigned short h) {
    return __uint_as_float(((unsigned)h) << 16);
}

// ---------- CSR build ----------
__global__ void hist_kernel(const int* __restrict__ edst, int* __restrict__ deg) {
    int e = blockIdx.x * 256 + threadIdx.x;
    if (e >= ET) return;
    int d = (e < NE) ? edst[e] : (e - NE);
    atomicAdd(&deg[d], 1);
}

// phase A: per-block sums of deg
__global__ void scanA(const int* __restrict__ deg, int* __restrict__ bsum) {
    __shared__ int sh[256];
    int t = threadIdx.x, i = blockIdx.x * 256 + t;
    sh[t] = (i < NN) ? deg[i] : 0;
    __syncthreads();
    for (int off = 128; off > 0; off >>= 1) {
        if (t < off) sh[t] += sh[t + off];
        __syncthreads();
    }
    if (t == 0) bsum[blockIdx.x] = sh[0];
}

// phase B: exclusive scan of 98 block sums (single small block)
__global__ void scanB(const int* __restrict__ bsum, int* __restrict__ boff,
                      int* __restrict__ rowptr) {
    __shared__ int sh[128];
    int t = threadIdx.x;
    int v = (t < NBLK_SCAN) ? bsum[t] : 0;
    sh[t] = v;
    __syncthreads();
    for (int off = 1; off < 128; off <<= 1) {
        int u = (t >= off) ? sh[t - off] : 0;
        __syncthreads();
        sh[t] += u;
        __syncthreads();
    }
    if (t < NBLK_SCAN) boff[t] = sh[t] - v;
    if (t == 0) rowptr[NN] = ET;
}

// phase C: local exclusive scan + block offset -> rowptr, cursor
__global__ void scanC(const int* __restrict__ deg, const int* __restrict__ boff,
                      int* __restrict__ rowptr, int* __restrict__ cursor) {
    __shared__ int sh[256];
    int t = threadIdx.x, i = blockIdx.x * 256 + t;
    int v = (i < NN) ? deg[i] : 0;
    sh[t] = v;
    __syncthreads();
    for (int off = 1; off < 256; off <<= 1) {
        int u = (t >= off) ? sh[t - off] : 0;
        __syncthreads();
        sh[t] += u;
        __syncthreads();
    }
    if (i < NN) {
        int ex = boff[blockIdx.x] + sh[t] - v;
        rowptr[i] = ex;
        cursor[i] = ex;
    }
}

__global__ void scatter_kernel(const int* __restrict__ esrc, const int* __restrict__ edst,
                               int* __restrict__ cursor, int* __restrict__ srcs) {
    int e = blockIdx.x * 256 + threadIdx.x;
    if (e >= ET) return;
    int s, d;
    if (e < NE) { s = esrc[e]; d = edst[e]; }
    else        { s = e - NE; d = s; }
    int p = atomicAdd(&cursor[d], 1);
    srcs[p] = s;
}

// ---------- xw = bn(x) @ W  (bf16 out, [n][h][c]) + xu = bn(x) @ U ----------
template<int D, bool BN>
__global__ void xw_kernel(const float* __restrict__ x, const float* __restrict__ W,
                          const float* __restrict__ U, const float* __restrict__ ss,
                          unsigned short* __restrict__ xwb, float* __restrict__ xu) {
    const int NB = 8;  // 25000 % 8 == 0
    __shared__ float xs[NB][D];
    int base = blockIdx.x * NB;
    int tid = threadIdx.x;
    for (int i = tid; i < NB * D; i += 256) {
        int n = i / D, k = i % D;
        float v = x[(size_t)(base + n) * D + k];
        if (BN) v = v * ss[k] + ss[64 + k];
        xs[n][k] = v;
    }
    __syncthreads();
    float acc[NB];
#pragma unroll
    for (int i = 0; i < NB; i++) acc[i] = 0.f;
    int j = tid;  // h*64+c
    for (int k = 0; k < D; k++) {
        float w = W[k * 256 + j];
#pragma unroll
        for (int i = 0; i < NB; i++) acc[i] += xs[i][k] * w;
    }
#pragma unroll
    for (int i = 0; i < NB; i++) xwb[(size_t)(base + i) * 256 + j] = f2bf(acc[i]);
    // xu: threads 0..31 -> (node, head)
    if (tid < NB * 4) {
        int n = tid >> 2, h = tid & 3;
        float s = 0.f;
        for (int k = 0; k < D; k++) s += xs[n][k] * U[k * 4 + h];
        xu[(size_t)(base + n) * 4 + h] = s;
    }
}

// ---------- edge aggregation: wave per dst ----------
template<bool RELU_BN>
__global__ void edge_kernel(const int* __restrict__ rowptr, const int* __restrict__ srcs,
                            const unsigned short* __restrict__ xwb, const float* __restrict__ xu,
                            const float* __restrict__ cvec, const float* __restrict__ bias,
                            float* __restrict__ y, float* __restrict__ bnpart) {
    int wid = threadIdx.x >> 6, lane = threadIdx.x & 63;
    int d = blockIdx.x * 4 + wid;  // grid 6250 * 4 waves == 25000 exactly
    __shared__ float sbuf[4][64], sqbuf[4][64];

    float c0 = cvec[0], c1 = cvec[1], c2 = cvec[2], c3 = cvec[3];
    int beg = rowptr[d], end = rowptr[d + 1];
    float xd0 = xu[d * 4 + 0], xd1 = xu[d * 4 + 1], xd2 = xu[d * 4 + 2], xd3 = xu[d * 4 + 3];
    float acc = 0.f;
    int s = srcs[beg];
    for (int i = beg; i < end; i++) {
        int snext = (i + 1 < end) ? srcs[i + 1] : s;
        float4 us = *(const float4*)&xu[s * 4];
        float l0 = xd0 - us.x + c0;
        float l1 = xd1 - us.y + c1;
        float l2 = xd2 - us.z + c2;
        float l3 = xd3 - us.w + c3;
        float mx = fmaxf(fmaxf(l0, l1), fmaxf(l2, l3));
        float e0 = __expf(l0 - mx), e1 = __expf(l1 - mx), e2 = __expf(l2 - mx), e3 = __expf(l3 - mx);
        float inv = 1.f / (e0 + e1 + e2 + e3);
        const unsigned short* r = xwb + (size_t)s * 256 + lane;
        float w0 = bf2f(r[0]), w1 = bf2f(r[64]), w2 = bf2f(r[128]), w3 = bf2f(r[192]);
        acc += inv * (e0 * w0 + e1 * w1 + e2 * w2 + e3 * w3);
        s = snext;
    }
    float v = acc / (float)(end - beg) + bias[lane];
    if (RELU_BN) v = fmaxf(v, 0.f);
    y[(size_t)d * 64 + lane] = v;

    if (RELU_BN) {
        sbuf[wid][lane] = v;
        sqbuf[wid][lane] = v * v;
        __syncthreads();
        if (threadIdx.x < 64) {
            float ts = sbuf[0][threadIdx.x] + sbuf[1][threadIdx.x] + sbuf[2][threadIdx.x] + sbuf[3][threadIdx.x];
            float tq = sqbuf[0][threadIdx.x] + sqbuf[1][threadIdx.x] + sqbuf[2][threadIdx.x] + sqbuf[3][threadIdx.x];
            int p = blockIdx.x & 63;
            atomicAdd(&bnpart[p * 128 + threadIdx.x], ts);
            atomicAdd(&bnpart[p * 128 + 64 + threadIdx.x], tq);
        }
    }
}

// ---------- BN stats -> scale/shift (256 threads, 4-way split reduction) ----------
__global__ void bnprep(const float* __restrict__ bnpart, const float* __restrict__ g,
                       const float* __restrict__ be, float* __restrict__ ss) {
    __shared__ float sb[4][64], qb[4][64];
    int t = threadIdx.x, grp = t >> 6, ch = t & 63;
    float s = 0.f, q = 0.f;
    for (int p = grp * 16; p < grp * 16 + 16; p++) {
        s += bnpart[p * 128 + ch];
        q += bnpart[p * 128 + 64 + ch];
    }
    sb[grp][ch] = s;
    qb[grp][ch] = q;
    __syncthreads();
    if (t < 64) {
        float S = sb[0][t] + sb[1][t] + sb[2][t] + sb[3][t];
        float Q = qb[0][t] + qb[1][t] + qb[2][t] + qb[3][t];
        float m = S * (1.0f / NN);
        float var = Q * (1.0f / NN) - m * m;
        float sc = g[t] * rsqrtf(var + 1e-5f);
        ss[t] = sc;
        ss[64 + t] = be[t] - m * sc;
    }
}

extern "C" void kernel_launch(void* const* d_in, const int* in_sizes, int n_in,
                              void* d_out, int out_size, void* d_ws, size_t ws_size,
                              hipStream_t stream) {
    const float* x    = (const float*)d_in[0];
    const int*   ei   = (const int*)d_in[1];
    const int*   esrc = ei;
    const int*   edst = ei + NE;
    const float* w0 = (const float*)d_in[2];
    const float* u0 = (const float*)d_in[3];
    const float* c0 = (const float*)d_in[4];
    const float* b0 = (const float*)d_in[5];
    const float* w1 = (const float*)d_in[6];
    const float* u1 = (const float*)d_in[7];
    const float* c1 = (const float*)d_in[8];
    const float* b1 = (const float*)d_in[9];
    const float* w2 = (const float*)d_in[10];
    const float* u2 = (const float*)d_in[11];
    const float* c2 = (const float*)d_in[12];
    const float* b2 = (const float*)d_in[13];
    const float* g0 = (const float*)d_in[14];
    const float* be0= (const float*)d_in[15];
    const float* g1 = (const float*)d_in[16];
    const float* be1= (const float*)d_in[17];
    float* out = (float*)d_out;

    char* ws = (char*)d_ws;
    size_t off = 0;
    auto alloc = [&](size_t bytes) { char* p = ws + off; off += (bytes + 255) & ~(size_t)255; return p; };
    float*          xu     = (float*)alloc((size_t)NN * 4 * sizeof(float));
    float*          y      = (float*)alloc((size_t)NN * 64 * sizeof(float));
    unsigned short* xwb    = (unsigned short*)alloc((size_t)NN * 256 * sizeof(unsigned short));
    int*            deg    = (int*)alloc((size_t)NN * sizeof(int));
    int*            rowptr = (int*)alloc((size_t)(NN + 1) * sizeof(int));
    int*            cursor = (int*)alloc((size_t)NN * sizeof(int));
    int*            srcs   = (int*)alloc((size_t)ET * sizeof(int));
    int*            bsum   = (int*)alloc((size_t)NBLK_SCAN * sizeof(int));
    int*            boff   = (int*)alloc((size_t)NBLK_SCAN * sizeof(int));
    float*          bnpart = (float*)alloc(64 * 128 * sizeof(float));
    float*          ss     = (float*)alloc(128 * sizeof(float));

    const int EG = (ET + 255) / 256;

    // ---- CSR build (dst-sorted; shared by all 3 layers) ----
    hipMemsetAsync(deg, 0, (size_t)NN * sizeof(int), stream);
    hist_kernel<<<EG, 256, 0, stream>>>(edst, deg);
    scanA<<<NBLK_SCAN, 256, 0, stream>>>(deg, bsum);
    scanB<<<1, 128, 0, stream>>>(bsum, boff, rowptr);
    scanC<<<NBLK_SCAN, 256, 0, stream>>>(deg, boff, rowptr, cursor);
    scatter_kernel<<<EG, 256, 0, stream>>>(esrc, edst, cursor, srcs);

    // ---- layer 0 (D=32, no BN on input) ----
    hipMemsetAsync(bnpart, 0, 64 * 128 * sizeof(float), stream);
    xw_kernel<32, false><<<NN / 8, 256, 0, stream>>>(x, w0, u0, nullptr, xwb, xu);
    edge_kernel<true><<<NN / 4, 256, 0, stream>>>(rowptr, srcs, xwb, xu, c0, b0, y, bnpart);
    bnprep<<<1, 256, 0, stream>>>(bnpart, g0, be0, ss);

    // ---- layer 1 (D=64, BN0 applied on load) ----
    hipMemsetAsync(bnpart, 0, 64 * 128 * sizeof(float), stream);
    xw_kernel<64, true><<<NN / 8, 256, 0, stream>>>(y, w1, u1, ss, xwb, xu);
    edge_kernel<true><<<NN / 4, 256, 0, stream>>>(rowptr, srcs, xwb, xu, c1, b1, y, bnpart);
    bnprep<<<1, 256, 0, stream>>>(bnpart, g1, be1, ss);

    // ---- layer 2 (D=64, BN1 applied on load, raw output) ----
    xw_kernel<64, true><<<NN / 8, 256, 0, stream>>>(y, w2, u2, ss, xwb, xu);
    edge_kernel<false><<<NN / 4, 256, 0, stream>>>(rowptr, srcs, xwb, xu, c2, b2, out, nullptr);
}